// Round 1
// baseline (1070.836 us; speedup 1.0000x reference)
//
#include <hip/hip_runtime.h>

#define B_ 2
#define T_ 8
#define Z_ 20
#define Y_ 64
#define X_ 64
#define C_ 2
#define F1_ 32
#define F_ 32

constexpr int NPTS     = B_*T_*Z_*Y_*X_;    // 1,310,720 (b,t,z,y,x) points
constexpr int SP_ELEMS = NPTS * F1_;        // 41,943,040 per component
constexpr int WX_ELEMS = 27 * C_ * F1_;     // 1728
constexpr int WT_ELEMS = 3 * F1_ * F_;      // 3072

// ---------------------------------------------------------------------------
// Weight projection: zero-mean (spatial only) + bound-norm per output filter.
// blocks 0..31  -> spatial filter f1 = blockIdx (54 elems each, reduce+proj)
// blocks 32..63 -> temporal filter f = blockIdx-32 (96 elems each, norm only)
// 64 threads/block (one wave).
// ---------------------------------------------------------------------------
__global__ __launch_bounds__(64) void project_kernel(
    const float* __restrict__ wxr, const float* __restrict__ wxi,
    const float* __restrict__ wtr, const float* __restrict__ wti,
    float* __restrict__ owr, float* __restrict__ owi,
    float* __restrict__ otr, float* __restrict__ oti)
{
    const int bid  = blockIdx.x;
    const int lane = threadIdx.x;

    if (bid < F1_) {
        const int f = bid;
        float er = 0.f, ei = 0.f;
        if (lane < 54) { er = wxr[lane*F1_ + f]; ei = wxi[lane*F1_ + f]; }
        // mean over 54 elements (r and i separately)
        float sr = er, si = ei;
        #pragma unroll
        for (int o = 32; o >= 1; o >>= 1) { sr += __shfl_xor(sr, o); si += __shfl_xor(si, o); }
        const float mr = sr * (1.f/54.f), mi = si * (1.f/54.f);
        const float dr = er - mr, di = ei - mi;
        float sq = (lane < 54) ? (dr*dr + di*di) : 0.f;
        #pragma unroll
        for (int o = 32; o >= 1; o >>= 1) sq += __shfl_xor(sq, o);
        const float s = 1.f / fmaxf(sqrtf(sq), 1.f);
        if (lane < 54) { owr[lane*F1_ + f] = dr*s; owi[lane*F1_ + f] = di*s; }
    } else {
        const int f = bid - F1_;
        float er[2], ei[2];
        float sq = 0.f;
        #pragma unroll
        for (int k = 0; k < 2; ++k) {
            const int e = lane + k*64;   // 0..95 valid (3*32 = 96 elems)
            if (e < 96) { er[k] = wtr[e*F_ + f]; ei[k] = wti[e*F_ + f]; sq += er[k]*er[k] + ei[k]*ei[k]; }
            else        { er[k] = 0.f;  ei[k] = 0.f; }
        }
        #pragma unroll
        for (int o = 32; o >= 1; o >>= 1) sq += __shfl_xor(sq, o);
        const float s = 1.f / fmaxf(sqrtf(sq), 1.f);
        #pragma unroll
        for (int k = 0; k < 2; ++k) {
            const int e = lane + k*64;
            if (e < 96) { otr[e*F_ + f] = er[k]*s; oti[e*F_ + f] = ei[k]*s; }
        }
    }
}

// ---------------------------------------------------------------------------
// Spatial 3x3x3 complex conv with symmetric padding (pad=1 each side of Z,Y,X).
// Thread = one (b,t,z,y,x) point, accumulates all 32 F1 outputs (r+i) in regs.
// Weights broadcast from LDS.
// ---------------------------------------------------------------------------
__global__ __launch_bounds__(256) void spatial_kernel(
    const float* __restrict__ xr, const float* __restrict__ xi,
    const float* __restrict__ wr, const float* __restrict__ wi,
    float* __restrict__ spr, float* __restrict__ spi)
{
    __shared__ float s_wr[WX_ELEMS];
    __shared__ float s_wi[WX_ELEMS];
    for (int i = threadIdx.x; i < WX_ELEMS; i += 256) { s_wr[i] = wr[i]; s_wi[i] = wi[i]; }
    __syncthreads();

    const int p   = blockIdx.x * 256 + threadIdx.x;
    const int x   = p & 63;
    const int y   = (p >> 6) & 63;
    const int zbt = p >> 12;
    const int z   = zbt % Z_;
    const int bt  = zbt / Z_;
    const int btbase = bt * (Z_*Y_*X_);

    float accr[F1_], acci[F1_];
    #pragma unroll
    for (int f = 0; f < F1_; ++f) { accr[f] = 0.f; acci[f] = 0.f; }

    #pragma unroll 1
    for (int kz = 0; kz < 3; ++kz) {
        int zz = z + kz - 1; zz = zz < 0 ? -zz-1 : (zz >= Z_ ? 2*Z_-1-zz : zz);
        #pragma unroll 1
        for (int ky = 0; ky < 3; ++ky) {
            int yy = y + ky - 1; yy = yy < 0 ? -yy-1 : (yy >= Y_ ? 2*Y_-1-yy : yy);
            #pragma unroll
            for (int kx = 0; kx < 3; ++kx) {
                int xx = x + kx - 1; xx = xx < 0 ? -xx-1 : (xx >= X_ ? 2*X_-1-xx : xx);
                const int ip = (btbase + zz*(Y_*X_) + yy*X_ + xx) * C_;
                const float2 vr = *reinterpret_cast<const float2*>(xr + ip);
                const float2 vi = *reinterpret_cast<const float2*>(xi + ip);
                const int wb = ((kz*3 + ky)*3 + kx) * (C_*F1_);
                #pragma unroll
                for (int f = 0; f < F1_; ++f) {
                    const float w0r = s_wr[wb + f],       w0i = s_wi[wb + f];
                    const float w1r = s_wr[wb + F1_ + f], w1i = s_wi[wb + F1_ + f];
                    accr[f] += vr.x*w0r - vi.x*w0i + vr.y*w1r - vi.y*w1i;
                    acci[f] += vr.x*w0i + vi.x*w0r + vr.y*w1i + vi.y*w1r;
                }
            }
        }
    }

    const size_t ob = (size_t)p * F1_;
    #pragma unroll
    for (int f = 0; f < F1_; f += 4) {
        *reinterpret_cast<float4*>(spr + ob + f) = make_float4(accr[f], accr[f+1], accr[f+2], accr[f+3]);
        *reinterpret_cast<float4*>(spi + ob + f) = make_float4(acci[f], acci[f+1], acci[f+2], acci[f+3]);
    }
}

// ---------------------------------------------------------------------------
// Temporal (3,1,1) complex conv over T with symmetric padding (pad=1 == clamp).
// Thread = one (b,t,z,y,x) point, all 32 F outputs (r+i) in regs.
// ---------------------------------------------------------------------------
__global__ __launch_bounds__(256) void temporal_kernel(
    const float* __restrict__ spr, const float* __restrict__ spi,
    const float* __restrict__ wr, const float* __restrict__ wi,
    float* __restrict__ yr, float* __restrict__ yi)
{
    __shared__ float s_wr[WT_ELEMS];
    __shared__ float s_wi[WT_ELEMS];
    for (int i = threadIdx.x; i < WT_ELEMS; i += 256) { s_wr[i] = wr[i]; s_wi[i] = wi[i]; }
    __syncthreads();

    const int p      = blockIdx.x * 256 + threadIdx.x;
    const int sp_idx = p % (Z_*Y_*X_);
    const int bt     = p / (Z_*Y_*X_);
    const int t      = bt % T_;
    const int b      = bt / T_;

    float accr[F_], acci[F_];
    #pragma unroll
    for (int f = 0; f < F_; ++f) { accr[f] = 0.f; acci[f] = 0.f; }

    #pragma unroll 1
    for (int kt = 0; kt < 3; ++kt) {
        int tt = t + kt - 1; tt = tt < 0 ? 0 : (tt >= T_ ? T_-1 : tt);  // sym pad=1
        const size_t sb = ((size_t)(b*T_ + tt) * (Z_*Y_*X_) + sp_idx) * F1_;
        #pragma unroll 1
        for (int f1 = 0; f1 < F1_; f1 += 4) {
            const float4 sr = *reinterpret_cast<const float4*>(spr + sb + f1);
            const float4 si = *reinterpret_cast<const float4*>(spi + sb + f1);
            const float srs[4] = {sr.x, sr.y, sr.z, sr.w};
            const float sis[4] = {si.x, si.y, si.z, si.w};
            #pragma unroll
            for (int j = 0; j < 4; ++j) {
                const int wb = (kt*F1_ + f1 + j) * F_;
                const float a = srs[j], bb = sis[j];
                #pragma unroll
                for (int f = 0; f < F_; ++f) {
                    const float wwr = s_wr[wb + f], wwi = s_wi[wb + f];
                    accr[f] += a*wwr - bb*wwi;
                    acci[f] += a*wwi + bb*wwr;
                }
            }
        }
    }

    const size_t ob = (size_t)p * F_;
    #pragma unroll
    for (int f = 0; f < F_; f += 4) {
        *reinterpret_cast<float4*>(yr + ob + f) = make_float4(accr[f], accr[f+1], accr[f+2], accr[f+3]);
        *reinterpret_cast<float4*>(yi + ob + f) = make_float4(acci[f], acci[f+1], acci[f+2], acci[f+3]);
    }
}

extern "C" void kernel_launch(void* const* d_in, const int* in_sizes, int n_in,
                              void* d_out, int out_size, void* d_ws, size_t ws_size,
                              hipStream_t stream)
{
    const float* xr  = (const float*)d_in[0];
    const float* xi  = (const float*)d_in[1];
    const float* wxr = (const float*)d_in[2];
    const float* wxi = (const float*)d_in[3];
    const float* wtr = (const float*)d_in[4];
    const float* wti = (const float*)d_in[5];

    float* ws   = (float*)d_ws;
    float* pwr  = ws;                    // 1728 projected spatial weights (r)
    float* pwi  = pwr + WX_ELEMS;        // 1728 (i)
    float* ptr_ = pwi + WX_ELEMS;        // 3072 projected temporal weights (r)
    float* pti  = ptr_ + WT_ELEMS;       // 3072 (i)
    float* spr  = ws + 16384;            // 41,943,040 (64KB-aligned region)
    float* spi  = spr + SP_ELEMS;        // 41,943,040

    float* yr = (float*)d_out;
    float* yi = yr + (size_t)NPTS * F_;

    hipLaunchKernelGGL(project_kernel, dim3(64), dim3(64), 0, stream,
                       wxr, wxi, wtr, wti, pwr, pwi, ptr_, pti);
    hipLaunchKernelGGL(spatial_kernel, dim3(NPTS/256), dim3(256), 0, stream,
                       xr, xi, pwr, pwi, spr, spi);
    hipLaunchKernelGGL(temporal_kernel, dim3(NPTS/256), dim3(256), 0, stream,
                       spr, spi, ptr_, pti, yr, yi);
}